// Round 2
// baseline (294.766 us; speedup 1.0000x reference)
//
#include <hip/hip_runtime.h>

typedef __bf16 bf16x8 __attribute__((ext_vector_type(8)));
typedef float f32x4 __attribute__((ext_vector_type(4)));
typedef unsigned short u16;

__device__ __forceinline__ u16 f2bf(float f){
  union { float fp; unsigned int u; } v; v.fp = f;
  unsigned int r = v.u + 0x7fffu + ((v.u >> 16) & 1u);
  return (u16)(r >> 16);
}

// ---------------- convert x (fp32 -> bf16), vectorized ----------------
__global__ __launch_bounds__(256) void convert_x_k(const float* __restrict__ in, u16* __restrict__ out, int n4){
  int stride = gridDim.x * blockDim.x;
  for (int i = blockIdx.x*blockDim.x + threadIdx.x; i < n4; i += stride){
    float4 v = ((const float4*)in)[i];
    ushort4 o;
    o.x = f2bf(v.x); o.y = f2bf(v.y); o.z = f2bf(v.z); o.w = f2bf(v.w);
    ((ushort4*)out)[i] = o;
  }
}

// ---------------- transpose+convert the four 1024x1024 weights ----------------
__global__ __launch_bounds__(256) void transpose_w_k(const float* __restrict__ W0, const float* __restrict__ W1,
                                                     const float* __restrict__ W2, const float* __restrict__ W3,
                                                     u16* __restrict__ Wt){
  __shared__ float tile[32][33];
  const float* W = (blockIdx.z==0)?W0:(blockIdx.z==1)?W1:(blockIdx.z==2)?W2:W3;
  u16* dst = Wt + ((size_t)blockIdx.z<<20);
  int tx = threadIdx.x, ty = threadIdx.y;
  int x = blockIdx.x*32 + tx;
  int y0 = blockIdx.y*32;
  #pragma unroll
  for (int i=0;i<32;i+=8) tile[ty+i][tx] = W[(size_t)(y0+ty+i)*1024 + x];
  __syncthreads();
  int xo = y0 + tx;
  #pragma unroll
  for (int i=0;i<32;i+=8) dst[(size_t)(blockIdx.x*32+ty+i)*1024 + xo] = f2bf(tile[tx][ty+i]);
}

// ---------------- RoPE cos/sin tables: [2048][64] fp32 each ----------------
__global__ __launch_bounds__(256) void rope_tables_k(float* __restrict__ cosT, float* __restrict__ sinT){
  int i = blockIdx.x*256 + threadIdx.x;      // 131072 total
  int si = i>>6, dd = i&63, f = dd&31;
  float invf = exp2f(-13.287712379549449f * (float)f * (1.0f/32.0f)); // 10000^(-f/32)
  float ang = (float)si * invf;
  float s, c;
  sincosf(ang, &s, &c);
  cosT[i] = c; sinT[i] = s;
}

// ---------------- QKV GEMM (x@W) + RoPE + head-split layouts ----------------
// Q,K -> [b][h][s][hd] bf16 (roped); V -> [b][h][hd][s] bf16 (transposed)
__global__ __launch_bounds__(256) void gemm_qkv_k(const u16* __restrict__ xb, const u16* __restrict__ Wt,
                                                  const float* __restrict__ cosT, const float* __restrict__ sinT,
                                                  u16* __restrict__ Qr, u16* __restrict__ Kr, u16* __restrict__ Vt){
  __shared__ __align__(16) u16 As[128*40];
  __shared__ __align__(16) u16 Bs[128*40];
  const int tid = threadIdx.x;
  const int w = tid>>6, lane = tid&63, quad = lane>>4, l15 = lane&15;
  const int wrow = w>>1, wcol = w&1;
  const int m0 = blockIdx.x*128;
  const int nG0 = blockIdx.y*128;
  const int which = nG0>>10, n0 = nG0&1023;
  const u16* __restrict__ B = Wt + ((size_t)which<<20);
  f32x4 acc[4][4] = {};
  const int r0 = tid>>2, sg = (tid&3)*8;
  const int r1 = r0 + 64;

  for (int kb=0; kb<1024; kb+=32){
    *(uint4*)&As[r0*40 + sg] = *(const uint4*)&xb[(size_t)(m0+r0)*1024 + kb + sg];
    *(uint4*)&Bs[r0*40 + sg] = *(const uint4*)&B [(size_t)(n0+r0)*1024 + kb + sg];
    *(uint4*)&As[r1*40 + sg] = *(const uint4*)&xb[(size_t)(m0+r1)*1024 + kb + sg];
    *(uint4*)&Bs[r1*40 + sg] = *(const uint4*)&B [(size_t)(n0+r1)*1024 + kb + sg];
    __syncthreads();
    bf16x8 a[4], b[4];
    #pragma unroll
    for (int t=0;t<4;t++){
      a[t] = *(const bf16x8*)&As[(64*wrow + 16*t + l15)*40 + quad*8];
      b[t] = *(const bf16x8*)&Bs[(64*wcol + 16*t + l15)*40 + quad*8];
    }
    #pragma unroll
    for (int ti=0;ti<4;ti++)
      #pragma unroll
      for (int tj=0;tj<4;tj++)
        acc[ti][tj] = __builtin_amdgcn_mfma_f32_16x16x32_bf16(a[ti], b[tj], acc[ti][tj], 0,0,0);
    __syncthreads();
  }

  const int colbase = n0 + 64*wcol;     // 64-aligned
  const int hh = colbase>>6;
  const int rowbase = m0 + 64*wrow + 4*quad;

  if (which < 2){
    u16* __restrict__ out = (which==0) ? Qr : Kr;
    #pragma unroll
    for (int tj=0;tj<4;tj++){
      int dd = 16*tj + l15;
      float sgn = (tj<2) ? -1.0f : 1.0f;
      int pj = tj^2;
      #pragma unroll
      for (int ti=0;ti<4;ti++){
        #pragma unroll
        for (int r=0;r<4;r++){
          int m = rowbase + 16*ti + r;
          int bi = m>>11, si = m&2047;
          float cs = cosT[(si<<6)+dd];
          float sn = sinT[(si<<6)+dd];
          float vv = acc[ti][tj][r]*cs + sgn*acc[ti][pj][r]*sn;
          out[(((size_t)(bi*16+hh)<<11) + si)*64 + dd] = f2bf(vv);
        }
      }
    }
  } else {
    #pragma unroll
    for (int tj=0;tj<4;tj++){
      int dd = 16*tj + l15;
      #pragma unroll
      for (int ti=0;ti<4;ti++){
        int m = rowbase + 16*ti;      // r=0..3 are consecutive si
        int bi = m>>11, si = m&2047;
        ushort4 pk;
        pk.x = f2bf(acc[ti][tj][0]); pk.y = f2bf(acc[ti][tj][1]);
        pk.z = f2bf(acc[ti][tj][2]); pk.w = f2bf(acc[ti][tj][3]);
        *(ushort4*)&Vt[(((size_t)(bi*16+hh)<<6) + dd)*2048 + si] = pk;
      }
    }
  }
}

// ---------------- flash attention, causal, online softmax ----------------
// grid (16 q-tiles of 128, 32 bh); block 256 = 4 waves, 32 q-rows/wave
__global__ __launch_bounds__(256) void attn_k(const u16* __restrict__ Qr, const u16* __restrict__ Kr,
                                              const u16* __restrict__ Vt, u16* __restrict__ ctx){
  __shared__ __align__(16) u16 Ks[64*72];
  __shared__ __align__(16) u16 Vs[64*72];
  __shared__ __align__(16) u16 Ps[128*72];
  const int tid = threadIdx.x;
  const int w = tid>>6, lane = tid&63, quad = lane>>4, l15 = lane&15;
  const int q0 = blockIdx.x*128;
  const int bh = blockIdx.y;
  const u16* __restrict__ Qb = Qr + ((size_t)bh<<17);
  const u16* __restrict__ Kb = Kr + ((size_t)bh<<17);
  const u16* __restrict__ Vb = Vt + ((size_t)bh<<17);
  const float CEXP = 0.18033688011112042f;   // log2(e)/8

  bf16x8 qf[2][2];
  #pragma unroll
  for (int ti=0;ti<2;ti++)
    #pragma unroll
    for (int kh=0;kh<2;kh++)
      qf[ti][kh] = *(const bf16x8*)&Qb[(size_t)(q0 + 32*w + 16*ti + l15)*64 + 32*kh + quad*8];

  f32x4 o[2][4] = {};
  float mrow[2][4], lrow[2][4];
  #pragma unroll
  for (int ti=0;ti<2;ti++)
    #pragma unroll
    for (int r=0;r<4;r++){ mrow[ti][r] = -1e30f; lrow[ti][r] = 0.0f; }

  const int srow = tid>>3;        // 0..31
  const int scol = (tid&7)*8;     // 0..56 — full 64-col coverage
  const int nk = (q0>>6) + 2;

  for (int kt=0; kt<nk; kt++){
    const int k0 = kt*64;
    *(uint4*)&Ks[srow*72 + scol]      = *(const uint4*)&Kb[(size_t)(k0+srow)*64 + scol];
    *(uint4*)&Ks[(srow+32)*72 + scol] = *(const uint4*)&Kb[(size_t)(k0+srow+32)*64 + scol];
    *(uint4*)&Vs[srow*72 + scol]      = *(const uint4*)&Vb[(size_t)srow*2048 + k0 + scol];
    *(uint4*)&Vs[(srow+32)*72 + scol] = *(const uint4*)&Vb[(size_t)(srow+32)*2048 + k0 + scol];
    __syncthreads();

    // S = Q K^T  (per wave: 32 q-rows x 64 keys)
    f32x4 s[2][4] = {};
    bf16x8 kf[4][2];
    #pragma unroll
    for (int tj=0;tj<4;tj++)
      #pragma unroll
      for (int kh=0;kh<2;kh++)
        kf[tj][kh] = *(const bf16x8*)&Ks[(16*tj + l15)*72 + 32*kh + quad*8];
    #pragma unroll
    for (int ti=0;ti<2;ti++)
      #pragma unroll
      for (int tj=0;tj<4;tj++){
        s[ti][tj] = __builtin_amdgcn_mfma_f32_16x16x32_bf16(qf[ti][0], kf[tj][0], s[ti][tj], 0,0,0);
        s[ti][tj] = __builtin_amdgcn_mfma_f32_16x16x32_bf16(qf[ti][1], kf[tj][1], s[ti][tj], 0,0,0);
      }

    // causal mask (only needed near diagonal)
    if (k0 + 63 > q0 + 32*w){
      #pragma unroll
      for (int ti=0;ti<2;ti++)
        #pragma unroll
        for (int r=0;r<4;r++){
          int qg = q0 + 32*w + 16*ti + 4*quad + r;
          #pragma unroll
          for (int tj=0;tj<4;tj++){
            int kg = k0 + 16*tj + l15;
            if (kg > qg) s[ti][tj][r] = -1e30f;
          }
        }
    }

    // online softmax
    #pragma unroll
    for (int ti=0;ti<2;ti++){
      #pragma unroll
      for (int r=0;r<4;r++){
        float mx = fmaxf(fmaxf(s[ti][0][r], s[ti][1][r]), fmaxf(s[ti][2][r], s[ti][3][r]));
        #pragma unroll
        for (int off=1; off<16; off<<=1) mx = fmaxf(mx, __shfl_xor(mx, off, 64));
        float mold = mrow[ti][r];
        float mn = fmaxf(mold, mx);
        mrow[ti][r] = mn;
        float alpha = exp2f(CEXP*(mold - mn));
        float rs = 0.0f;
        int prow = (32*w + 16*ti + 4*quad + r)*72 + l15;
        #pragma unroll
        for (int tj=0;tj<4;tj++){
          float p = exp2f(CEXP*(s[ti][tj][r] - mn));
          rs += p;
          Ps[prow + 16*tj] = f2bf(p);
          o[ti][tj][r] *= alpha;
        }
        #pragma unroll
        for (int off=1; off<16; off<<=1) rs += __shfl_xor(rs, off, 64);
        lrow[ti][r] = lrow[ti][r]*alpha + rs;
      }
    }

    // O += P V   (P from LDS in A-layout, V^T in B-layout)
    bf16x8 pf[2][2], vf[4][2];
    #pragma unroll
    for (int ti=0;ti<2;ti++)
      #pragma unroll
      for (int kh=0;kh<2;kh++)
        pf[ti][kh] = *(const bf16x8*)&Ps[(32*w + 16*ti + l15)*72 + 32*kh + quad*8];
    #pragma unroll
    for (int tj=0;tj<4;tj++)
      #pragma unroll
      for (int kh=0;kh<2;kh++)
        vf[tj][kh] = *(const bf16x8*)&Vs[(16*tj + l15)*72 + 32*kh + quad*8];
    #pragma unroll
    for (int ti=0;ti<2;ti++)
      #pragma unroll
      for (int tj=0;tj<4;tj++){
        o[ti][tj] = __builtin_amdgcn_mfma_f32_16x16x32_bf16(pf[ti][0], vf[tj][0], o[ti][tj], 0,0,0);
        o[ti][tj] = __builtin_amdgcn_mfma_f32_16x16x32_bf16(pf[ti][1], vf[tj][1], o[ti][tj], 0,0,0);
      }
    __syncthreads();
  }

  // epilogue: ctx[b][s][h*64+dd] bf16
  const int bi = bh>>4, hh = bh&15;
  #pragma unroll
  for (int ti=0;ti<2;ti++){
    #pragma unroll
    for (int r=0;r<4;r++){
      float inv = 1.0f / lrow[ti][r];
      int sq = q0 + 32*w + 16*ti + 4*quad + r;
      u16* orow = ctx + (((size_t)(bi*2048 + sq))<<10) + (hh<<6);
      #pragma unroll
      for (int tj=0;tj<4;tj++)
        orow[16*tj + l15] = f2bf(o[ti][tj][r] * inv);
    }
  }
}

// ---------------- output GEMM: ctx @ W_o -> fp32 out ----------------
__global__ __launch_bounds__(256) void gemm_out_k(const u16* __restrict__ cb, const u16* __restrict__ Wot,
                                                  float* __restrict__ out){
  __shared__ __align__(16) u16 As[128*40];
  __shared__ __align__(16) u16 Bs[128*40];
  const int tid = threadIdx.x;
  const int w = tid>>6, lane = tid&63, quad = lane>>4, l15 = lane&15;
  const int wrow = w>>1, wcol = w&1;
  const int m0 = blockIdx.x*128;
  const int nG0 = blockIdx.y*128;
  f32x4 acc[4][4] = {};
  const int r0 = tid>>2, sg = (tid&3)*8;
  const int r1 = r0 + 64;

  for (int kb=0; kb<1024; kb+=32){
    *(uint4*)&As[r0*40 + sg] = *(const uint4*)&cb [(size_t)(m0+r0)*1024 + kb + sg];
    *(uint4*)&Bs[r0*40 + sg] = *(const uint4*)&Wot[(size_t)(nG0+r0)*1024 + kb + sg];
    *(uint4*)&As[r1*40 + sg] = *(const uint4*)&cb [(size_t)(m0+r1)*1024 + kb + sg];
    *(uint4*)&Bs[r1*40 + sg] = *(const uint4*)&Wot[(size_t)(nG0+r1)*1024 + kb + sg];
    __syncthreads();
    bf16x8 a[4], b[4];
    #pragma unroll
    for (int t=0;t<4;t++){
      a[t] = *(const bf16x8*)&As[(64*wrow + 16*t + l15)*40 + quad*8];
      b[t] = *(const bf16x8*)&Bs[(64*wcol + 16*t + l15)*40 + quad*8];
    }
    #pragma unroll
    for (int ti=0;ti<4;ti++)
      #pragma unroll
      for (int tj=0;tj<4;tj++)
        acc[ti][tj] = __builtin_amdgcn_mfma_f32_16x16x32_bf16(a[ti], b[tj], acc[ti][tj], 0,0,0);
    __syncthreads();
  }

  const int rowbase = m0 + 64*wrow + 4*quad;
  const int colb = nG0 + 64*wcol;
  #pragma unroll
  for (int ti=0;ti<4;ti++){
    #pragma unroll
    for (int r=0;r<4;r++){
      int m = rowbase + 16*ti + r;
      float* orow = out + (size_t)m*1024 + colb;
      #pragma unroll
      for (int tj=0;tj<4;tj++)
        orow[16*tj + l15] = acc[ti][tj][r];
    }
  }
}

extern "C" void kernel_launch(void* const* d_in, const int* in_sizes, int n_in,
                              void* d_out, int out_size, void* d_ws, size_t ws_size,
                              hipStream_t stream){
  const float* x  = (const float*)d_in[0];
  const float* Wq = (const float*)d_in[1];
  const float* Wk = (const float*)d_in[2];
  const float* Wv = (const float*)d_in[3];
  const float* Wo = (const float*)d_in[4];
  float* out = (float*)d_out;
  u16* ws = (u16*)d_ws;

  u16* XB  = ws;                    // x bf16            [4096][1024]   8 MB
  u16* WT  = ws + ((size_t)4<<20);  // Wq^T,Wk^T,Wv^T,Wo^T bf16         8 MB
  u16* QR  = ws + ((size_t)8<<20);  // Q roped  [b][h][s][hd]           8 MB
  u16* KR  = ws + ((size_t)12<<20); // K roped  [b][h][s][hd]           8 MB
  u16* VT  = ws + ((size_t)16<<20); // V^T      [b][h][hd][s]           8 MB
  u16* CTX = ws + ((size_t)20<<20); // ctx bf16 [4096][1024]            8 MB
  float* COS = (float*)(ws + ((size_t)24<<20));  // [2048][64]          512 KB
  float* SIN = COS + (1<<17);                    //                     512 KB

  convert_x_k  <<<512, 256, 0, stream>>>(x, XB, 1<<20);
  transpose_w_k<<<dim3(32,32,4), dim3(32,8), 0, stream>>>(Wq, Wk, Wv, Wo, WT);
  rope_tables_k<<<512, 256, 0, stream>>>(COS, SIN);
  gemm_qkv_k   <<<dim3(32,24), 256, 0, stream>>>(XB, WT, COS, SIN, QR, KR, VT);
  attn_k       <<<dim3(16,32), 256, 0, stream>>>(QR, KR, VT, CTX);
  gemm_out_k   <<<dim3(32,8), 256, 0, stream>>>(CTX, WT + ((size_t)3<<20), out);
}

// Round 3
// 255.867 us; speedup vs baseline: 1.1520x; 1.1520x over previous
//
#include <hip/hip_runtime.h>

typedef __bf16 bf16x8 __attribute__((ext_vector_type(8)));
typedef float f32x4 __attribute__((ext_vector_type(4)));
typedef unsigned short u16;

__device__ __forceinline__ u16 f2bf(float f){
  union { float fp; unsigned int u; } v; v.fp = f;
  unsigned int r = v.u + 0x7fffu + ((v.u >> 16) & 1u);
  return (u16)(r >> 16);
}

// ---------------- convert x (fp32 -> bf16), vectorized ----------------
__global__ __launch_bounds__(256) void convert_x_k(const float* __restrict__ in, u16* __restrict__ out, int n4){
  int stride = gridDim.x * blockDim.x;
  for (int i = blockIdx.x*blockDim.x + threadIdx.x; i < n4; i += stride){
    float4 v = ((const float4*)in)[i];
    ushort4 o;
    o.x = f2bf(v.x); o.y = f2bf(v.y); o.z = f2bf(v.z); o.w = f2bf(v.w);
    ((ushort4*)out)[i] = o;
  }
}

// ---------------- transpose+convert the four 1024x1024 weights ----------------
__global__ __launch_bounds__(256) void transpose_w_k(const float* __restrict__ W0, const float* __restrict__ W1,
                                                     const float* __restrict__ W2, const float* __restrict__ W3,
                                                     u16* __restrict__ Wt){
  __shared__ float tile[32][33];
  const float* W = (blockIdx.z==0)?W0:(blockIdx.z==1)?W1:(blockIdx.z==2)?W2:W3;
  u16* dst = Wt + ((size_t)blockIdx.z<<20);
  int tx = threadIdx.x, ty = threadIdx.y;
  int x = blockIdx.x*32 + tx;
  int y0 = blockIdx.y*32;
  #pragma unroll
  for (int i=0;i<32;i+=8) tile[ty+i][tx] = W[(size_t)(y0+ty+i)*1024 + x];
  __syncthreads();
  int xo = y0 + tx;
  #pragma unroll
  for (int i=0;i<32;i+=8) dst[(size_t)(blockIdx.x*32+ty+i)*1024 + xo] = f2bf(tile[tx][ty+i]);
}

// ---------------- RoPE cos/sin tables: [2048][64] fp32 each ----------------
__global__ __launch_bounds__(256) void rope_tables_k(float* __restrict__ cosT, float* __restrict__ sinT){
  int i = blockIdx.x*256 + threadIdx.x;      // 131072 total
  int si = i>>6, dd = i&63, f = dd&31;
  float invf = exp2f(-13.287712379549449f * (float)f * (1.0f/32.0f)); // 10000^(-f/32)
  float ang = (float)si * invf;
  float s, c;
  sincosf(ang, &s, &c);
  cosT[i] = c; sinT[i] = s;
}

// ---------------- QKV GEMM (x@W) + RoPE + head-split layouts ----------------
// Q -> [b][h][s][hd] bf16 (roped, PRE-SCALED by log2(e)/8); K -> [b][h][s][hd]; V -> [b][h][hd][s]
__global__ __launch_bounds__(256) void gemm_qkv_k(const u16* __restrict__ xb, const u16* __restrict__ Wt,
                                                  const float* __restrict__ cosT, const float* __restrict__ sinT,
                                                  u16* __restrict__ Qr, u16* __restrict__ Kr, u16* __restrict__ Vt){
  __shared__ __align__(16) u16 As[128*40];
  __shared__ __align__(16) u16 Bs[128*40];
  const int tid = threadIdx.x;
  const int w = tid>>6, lane = tid&63, quad = lane>>4, l15 = lane&15;
  const int wrow = w>>1, wcol = w&1;
  const int m0 = blockIdx.x*128;
  const int nG0 = blockIdx.y*128;
  const int which = nG0>>10, n0 = nG0&1023;
  const u16* __restrict__ B = Wt + ((size_t)which<<20);
  f32x4 acc[4][4] = {};
  const int r0 = tid>>2, sg = (tid&3)*8;
  const int r1 = r0 + 64;

  for (int kb=0; kb<1024; kb+=32){
    *(uint4*)&As[r0*40 + sg] = *(const uint4*)&xb[(size_t)(m0+r0)*1024 + kb + sg];
    *(uint4*)&Bs[r0*40 + sg] = *(const uint4*)&B [(size_t)(n0+r0)*1024 + kb + sg];
    *(uint4*)&As[r1*40 + sg] = *(const uint4*)&xb[(size_t)(m0+r1)*1024 + kb + sg];
    *(uint4*)&Bs[r1*40 + sg] = *(const uint4*)&B [(size_t)(n0+r1)*1024 + kb + sg];
    __syncthreads();
    bf16x8 a[4], b[4];
    #pragma unroll
    for (int t=0;t<4;t++){
      a[t] = *(const bf16x8*)&As[(64*wrow + 16*t + l15)*40 + quad*8];
      b[t] = *(const bf16x8*)&Bs[(64*wcol + 16*t + l15)*40 + quad*8];
    }
    #pragma unroll
    for (int ti=0;ti<4;ti++)
      #pragma unroll
      for (int tj=0;tj<4;tj++)
        acc[ti][tj] = __builtin_amdgcn_mfma_f32_16x16x32_bf16(a[ti], b[tj], acc[ti][tj], 0,0,0);
    __syncthreads();
  }

  const int colbase = n0 + 64*wcol;     // 64-aligned
  const int hh = colbase>>6;
  const int rowbase = m0 + 64*wrow + 4*quad;
  const float QSCALE = 0.18033688011112042f;  // log2(e)/8 folded into Q

  if (which < 2){
    u16* __restrict__ out = (which==0) ? Qr : Kr;
    const float osc = (which==0) ? QSCALE : 1.0f;
    #pragma unroll
    for (int tj=0;tj<4;tj++){
      int dd = 16*tj + l15;
      float sgn = (tj<2) ? -1.0f : 1.0f;
      int pj = tj^2;
      #pragma unroll
      for (int ti=0;ti<4;ti++){
        #pragma unroll
        for (int r=0;r<4;r++){
          int m = rowbase + 16*ti + r;
          int bi = m>>11, si = m&2047;
          float cs = cosT[(si<<6)+dd];
          float sn = sinT[(si<<6)+dd];
          float vv = (acc[ti][tj][r]*cs + sgn*acc[ti][pj][r]*sn) * osc;
          out[(((size_t)(bi*16+hh)<<11) + si)*64 + dd] = f2bf(vv);
        }
      }
    }
  } else {
    #pragma unroll
    for (int tj=0;tj<4;tj++){
      int dd = 16*tj + l15;
      #pragma unroll
      for (int ti=0;ti<4;ti++){
        int m = rowbase + 16*ti;      // r=0..3 are consecutive si
        int bi = m>>11, si = m&2047;
        ushort4 pk;
        pk.x = f2bf(acc[ti][tj][0]); pk.y = f2bf(acc[ti][tj][1]);
        pk.z = f2bf(acc[ti][tj][2]); pk.w = f2bf(acc[ti][tj][3]);
        *(ushort4*)&Vt[(((size_t)(bi*16+hh)<<6) + dd)*2048 + si] = pk;
      }
    }
  }
}

// ---------------- flash attention v2: S^T orientation, max-free softmax ----------------
// grid (8 tile-pairs, 32 bh); block 256 = 4 waves, 32 q-rows/wave, 128-row tiles
// Each block: phase A = q-tile 'pair', phase B = q-tile '15-pair' -> exactly 34 k-steps total.
__global__ __launch_bounds__(256,1) void attn_k(const u16* __restrict__ Qr, const u16* __restrict__ Kr,
                                                const u16* __restrict__ Vt, u16* __restrict__ ctx){
  __shared__ __align__(16) u16 Ks[64*72];
  __shared__ __align__(16) u16 Vs[64*72];
  __shared__ __align__(16) u16 Ps[4*32*72];   // wave-private P scratch
  const int tid = threadIdx.x;
  const int w = tid>>6, lane = tid&63, quad = lane>>4, l15 = lane&15;
  const int pair = blockIdx.x;
  const int bh = blockIdx.y;
  const u16* __restrict__ Qb = Qr + ((size_t)bh<<17);
  const u16* __restrict__ Kb = Kr + ((size_t)bh<<17);
  const u16* __restrict__ Vb = Vt + ((size_t)bh<<17);
  u16* __restrict__ Pw = Ps + w*32*72;
  const int srow = tid>>3;        // 0..31
  const int scol = (tid&7)*8;     // 0..56
  const int bi = bh>>4, hh = bh&15;

  for (int ph=0; ph<2; ph++){
    const int qt = ph ? (15-pair) : pair;
    const int q0 = qt*128;
    const int nk = (q0>>6) + 2;

    // Q fragments (B-operand): n = q-row on l15, k = d on quad*8+j. Q pre-scaled by log2(e)/8.
    bf16x8 qf[2][2];
    #pragma unroll
    for (int ti=0;ti<2;ti++)
      #pragma unroll
      for (int kh=0;kh<2;kh++)
        qf[ti][kh] = *(const bf16x8*)&Qb[(size_t)(q0 + 32*w + 16*ti + l15)*64 + 32*kh + quad*8];

    f32x4 o[2][4] = {};
    float lsum[2] = {0.0f, 0.0f};

    for (int kt=0; kt<nk; kt++){
      const int k0 = kt*64;
      *(uint4*)&Ks[srow*72 + scol]      = *(const uint4*)&Kb[(size_t)(k0+srow)*64 + scol];
      *(uint4*)&Ks[(srow+32)*72 + scol] = *(const uint4*)&Kb[(size_t)(k0+srow+32)*64 + scol];
      *(uint4*)&Vs[srow*72 + scol]      = *(const uint4*)&Vb[(size_t)srow*2048 + k0 + scol];
      *(uint4*)&Vs[(srow+32)*72 + scol] = *(const uint4*)&Vb[(size_t)(srow+32)*2048 + k0 + scol];
      __syncthreads();

      // K fragments (A-operand): m = key on l15, k = d on quad*8+j
      bf16x8 kf[4][2];
      #pragma unroll
      for (int tjk=0;tjk<4;tjk++)
        #pragma unroll
        for (int kh=0;kh<2;kh++)
          kf[tjk][kh] = *(const bf16x8*)&Ks[(16*tjk + l15)*72 + 32*kh + quad*8];

      // S^T = K Q^T : C col = q-row = l15, row = key = quad*4+r (+16*tjk)
      f32x4 st[2][4] = {};
      #pragma unroll
      for (int ti=0;ti<2;ti++)
        #pragma unroll
        for (int tjk=0;tjk<4;tjk++){
          st[ti][tjk] = __builtin_amdgcn_mfma_f32_16x16x32_bf16(kf[tjk][0], qf[ti][0], st[ti][tjk], 0,0,0);
          st[ti][tjk] = __builtin_amdgcn_mfma_f32_16x16x32_bf16(kf[tjk][1], qf[ti][1], st[ti][tjk], 0,0,0);
        }

      // max-free softmax: p = exp2(s) (scale folded into Q), in-lane over 16 keys
      #pragma unroll
      for (int ti=0;ti<2;ti++){
        const int qbase = q0 + 32*w + 16*ti;   // this lane's q-row = qbase + l15
        f32x4 p[4];
        if (k0 + 63 > qbase){                   // diagonal: apply causal mask
          const int qg = qbase + l15;
          #pragma unroll
          for (int tjk=0;tjk<4;tjk++)
            #pragma unroll
            for (int r=0;r<4;r++){
              int kg = k0 + 16*tjk + 4*quad + r;
              p[tjk][r] = (kg > qg) ? 0.0f : exp2f(fminf(st[ti][tjk][r], 80.0f));
            }
        } else {
          #pragma unroll
          for (int tjk=0;tjk<4;tjk++)
            #pragma unroll
            for (int r=0;r<4;r++)
              p[tjk][r] = exp2f(fminf(st[ti][tjk][r], 80.0f));
        }
        f32x4 t = (p[0]+p[1]) + (p[2]+p[3]);
        float rs = (t[0]+t[1]) + (t[2]+t[3]);
        rs += __shfl_xor(rs, 16, 64);
        rs += __shfl_xor(rs, 32, 64);
        lsum[ti] += rs;
        // pack P (bf16) -> wave-private LDS, row = q-row, col = key (natural A layout)
        #pragma unroll
        for (int tjk=0;tjk<4;tjk++){
          ushort4 pk;
          pk.x = f2bf(p[tjk][0]); pk.y = f2bf(p[tjk][1]);
          pk.z = f2bf(p[tjk][2]); pk.w = f2bf(p[tjk][3]);
          *(ushort4*)&Pw[(16*ti + l15)*72 + 16*tjk + 4*quad] = pk;
        }
      }

      // O += P V : A = P from LDS, B = V^T fragments
      bf16x8 pf[2][2], vf[4][2];
      #pragma unroll
      for (int ti=0;ti<2;ti++)
        #pragma unroll
        for (int kh=0;kh<2;kh++)
          pf[ti][kh] = *(const bf16x8*)&Pw[(16*ti + l15)*72 + 32*kh + quad*8];
      #pragma unroll
      for (int tjd=0;tjd<4;tjd++)
        #pragma unroll
        for (int kh=0;kh<2;kh++)
          vf[tjd][kh] = *(const bf16x8*)&Vs[(16*tjd + l15)*72 + 32*kh + quad*8];
      #pragma unroll
      for (int ti=0;ti<2;ti++)
        #pragma unroll
        for (int tjd=0;tjd<4;tjd++){
          o[ti][tjd] = __builtin_amdgcn_mfma_f32_16x16x32_bf16(pf[ti][0], vf[tjd][0], o[ti][tjd], 0,0,0);
          o[ti][tjd] = __builtin_amdgcn_mfma_f32_16x16x32_bf16(pf[ti][1], vf[tjd][1], o[ti][tjd], 0,0,0);
        }
      __syncthreads();
    }

    // epilogue: O C-layout col = d = 16*tjd+l15, row = q-row = quad*4+r (within ti group)
    #pragma unroll
    for (int ti=0;ti<2;ti++){
      #pragma unroll
      for (int r=0;r<4;r++){
        float lv = __shfl(lsum[ti], 4*quad + r, 64);   // l lives at lane l15 = q-row
        float inv = 1.0f / lv;
        int sq = q0 + 32*w + 16*ti + 4*quad + r;
        u16* orow = ctx + (((size_t)(bi*2048 + sq))<<10) + (hh<<6);
        #pragma unroll
        for (int tjd=0;tjd<4;tjd++)
          orow[16*tjd + l15] = f2bf(o[ti][tjd][r] * inv);
      }
    }
  }
}

// ---------------- output GEMM: ctx @ W_o -> fp32 out ----------------
__global__ __launch_bounds__(256) void gemm_out_k(const u16* __restrict__ cb, const u16* __restrict__ Wot,
                                                  float* __restrict__ out){
  __shared__ __align__(16) u16 As[128*40];
  __shared__ __align__(16) u16 Bs[128*40];
  const int tid = threadIdx.x;
  const int w = tid>>6, lane = tid&63, quad = lane>>4, l15 = lane&15;
  const int wrow = w>>1, wcol = w&1;
  const int m0 = blockIdx.x*128;
  const int nG0 = blockIdx.y*128;
  f32x4 acc[4][4] = {};
  const int r0 = tid>>2, sg = (tid&3)*8;
  const int r1 = r0 + 64;

  for (int kb=0; kb<1024; kb+=32){
    *(uint4*)&As[r0*40 + sg] = *(const uint4*)&cb [(size_t)(m0+r0)*1024 + kb + sg];
    *(uint4*)&Bs[r0*40 + sg] = *(const uint4*)&Wot[(size_t)(nG0+r0)*1024 + kb + sg];
    *(uint4*)&As[r1*40 + sg] = *(const uint4*)&cb [(size_t)(m0+r1)*1024 + kb + sg];
    *(uint4*)&Bs[r1*40 + sg] = *(const uint4*)&Wot[(size_t)(nG0+r1)*1024 + kb + sg];
    __syncthreads();
    bf16x8 a[4], b[4];
    #pragma unroll
    for (int t=0;t<4;t++){
      a[t] = *(const bf16x8*)&As[(64*wrow + 16*t + l15)*40 + quad*8];
      b[t] = *(const bf16x8*)&Bs[(64*wcol + 16*t + l15)*40 + quad*8];
    }
    #pragma unroll
    for (int ti=0;ti<4;ti++)
      #pragma unroll
      for (int tj=0;tj<4;tj++)
        acc[ti][tj] = __builtin_amdgcn_mfma_f32_16x16x32_bf16(a[ti], b[tj], acc[ti][tj], 0,0,0);
    __syncthreads();
  }

  const int rowbase = m0 + 64*wrow + 4*quad;
  const int colb = nG0 + 64*wcol;
  #pragma unroll
  for (int ti=0;ti<4;ti++){
    #pragma unroll
    for (int r=0;r<4;r++){
      int m = rowbase + 16*ti + r;
      float* orow = out + (size_t)m*1024 + colb;
      #pragma unroll
      for (int tj=0;tj<4;tj++)
        orow[16*tj + l15] = acc[ti][tj][r];
    }
  }
}

extern "C" void kernel_launch(void* const* d_in, const int* in_sizes, int n_in,
                              void* d_out, int out_size, void* d_ws, size_t ws_size,
                              hipStream_t stream){
  const float* x  = (const float*)d_in[0];
  const float* Wq = (const float*)d_in[1];
  const float* Wk = (const float*)d_in[2];
  const float* Wv = (const float*)d_in[3];
  const float* Wo = (const float*)d_in[4];
  float* out = (float*)d_out;
  u16* ws = (u16*)d_ws;

  u16* XB  = ws;                    // x bf16            [4096][1024]   8 MB
  u16* WT  = ws + ((size_t)4<<20);  // Wq^T,Wk^T,Wv^T,Wo^T bf16         8 MB
  u16* QR  = ws + ((size_t)8<<20);  // Q roped+scaled [b][h][s][hd]     8 MB
  u16* KR  = ws + ((size_t)12<<20); // K roped  [b][h][s][hd]           8 MB
  u16* VT  = ws + ((size_t)16<<20); // V^T      [b][h][hd][s]           8 MB
  u16* CTX = ws + ((size_t)20<<20); // ctx bf16 [4096][1024]            8 MB
  float* COS = (float*)(ws + ((size_t)24<<20));  // [2048][64]          512 KB
  float* SIN = COS + (1<<17);                    //                     512 KB

  convert_x_k  <<<512, 256, 0, stream>>>(x, XB, 1<<20);
  transpose_w_k<<<dim3(32,32,4), dim3(32,8), 0, stream>>>(Wq, Wk, Wv, Wo, WT);
  rope_tables_k<<<512, 256, 0, stream>>>(COS, SIN);
  gemm_qkv_k   <<<dim3(32,24), 256, 0, stream>>>(XB, WT, COS, SIN, QR, KR, VT);
  attn_k       <<<dim3(8,32), 256, 0, stream>>>(QR, KR, VT, CTX);
  gemm_out_k   <<<dim3(32,8), 256, 0, stream>>>(CTX, WT + ((size_t)3<<20), out);
}

// Round 5
// 236.737 us; speedup vs baseline: 1.2451x; 1.0808x over previous
//
#include <hip/hip_runtime.h>

typedef __bf16 bf16x8 __attribute__((ext_vector_type(8)));
typedef float f32x4 __attribute__((ext_vector_type(4)));
typedef unsigned short u16;

__device__ __forceinline__ u16 f2bf(float f){
  union { float fp; unsigned int u; } v; v.fp = f;
  unsigned int r = v.u + 0x7fffu + ((v.u >> 16) & 1u);
  return (u16)(r >> 16);
}

// ---------------- convert x (fp32 -> bf16), vectorized ----------------
__global__ __launch_bounds__(256) void convert_x_k(const float* __restrict__ in, u16* __restrict__ out, int n4){
  int stride = gridDim.x * blockDim.x;
  for (int i = blockIdx.x*blockDim.x + threadIdx.x; i < n4; i += stride){
    float4 v = ((const float4*)in)[i];
    ushort4 o;
    o.x = f2bf(v.x); o.y = f2bf(v.y); o.z = f2bf(v.z); o.w = f2bf(v.w);
    ((ushort4*)out)[i] = o;
  }
}

// ---------------- transpose+convert the four 1024x1024 weights ----------------
__global__ __launch_bounds__(256) void transpose_w_k(const float* __restrict__ W0, const float* __restrict__ W1,
                                                     const float* __restrict__ W2, const float* __restrict__ W3,
                                                     u16* __restrict__ Wt){
  __shared__ float tile[32][33];
  const float* W = (blockIdx.z==0)?W0:(blockIdx.z==1)?W1:(blockIdx.z==2)?W2:W3;
  u16* dst = Wt + ((size_t)blockIdx.z<<20);
  int tx = threadIdx.x, ty = threadIdx.y;
  int x = blockIdx.x*32 + tx;
  int y0 = blockIdx.y*32;
  #pragma unroll
  for (int i=0;i<32;i+=8) tile[ty+i][tx] = W[(size_t)(y0+ty+i)*1024 + x];
  __syncthreads();
  int xo = y0 + tx;
  #pragma unroll
  for (int i=0;i<32;i+=8) dst[(size_t)(blockIdx.x*32+ty+i)*1024 + xo] = f2bf(tile[tx][ty+i]);
}

// ---------------- RoPE cos/sin tables: [2048][64] fp32 each ----------------
__global__ __launch_bounds__(256) void rope_tables_k(float* __restrict__ cosT, float* __restrict__ sinT){
  int i = blockIdx.x*256 + threadIdx.x;      // 131072 total
  int si = i>>6, dd = i&63, f = dd&31;
  float invf = exp2f(-13.287712379549449f * (float)f * (1.0f/32.0f)); // 10000^(-f/32)
  float ang = (float)si * invf;
  float s, c;
  sincosf(ang, &s, &c);
  cosT[i] = c; sinT[i] = s;
}

// ---------------- QKV GEMM (x@W) + RoPE + fragment-swizzled layouts ----------------
// Q,K -> FRAG16[bh][tile16][kh][lane][8] (A/B-operand fragment-contiguous), Q pre-scaled log2(e)/8
// V   -> VF[bh][kt64][kh][tjd][lane][8]  (B-operand fragments for PV)
__global__ __launch_bounds__(256) void gemm_qkv_k(const u16* __restrict__ xb, const u16* __restrict__ Wt,
                                                  const float* __restrict__ cosT, const float* __restrict__ sinT,
                                                  u16* __restrict__ Qr, u16* __restrict__ Kr, u16* __restrict__ Vt){
  __shared__ __align__(16) u16 As[128*40];
  __shared__ __align__(16) u16 Bs[128*40];
  const int tid = threadIdx.x;
  const int w = tid>>6, lane = tid&63, quad = lane>>4, l15 = lane&15;
  const int wrow = w>>1, wcol = w&1;
  const int m0 = blockIdx.x*128;
  const int nG0 = blockIdx.y*128;
  const int which = nG0>>10, n0 = nG0&1023;
  const u16* __restrict__ B = Wt + ((size_t)which<<20);
  f32x4 acc[4][4] = {};
  const int r0 = tid>>2, sg = (tid&3)*8;
  const int r1 = r0 + 64;

  for (int kb=0; kb<1024; kb+=32){
    *(uint4*)&As[r0*40 + sg] = *(const uint4*)&xb[(size_t)(m0+r0)*1024 + kb + sg];
    *(uint4*)&Bs[r0*40 + sg] = *(const uint4*)&B [(size_t)(n0+r0)*1024 + kb + sg];
    *(uint4*)&As[r1*40 + sg] = *(const uint4*)&xb[(size_t)(m0+r1)*1024 + kb + sg];
    *(uint4*)&Bs[r1*40 + sg] = *(const uint4*)&B [(size_t)(n0+r1)*1024 + kb + sg];
    __syncthreads();
    bf16x8 a[4], b[4];
    #pragma unroll
    for (int t=0;t<4;t++){
      a[t] = *(const bf16x8*)&As[(64*wrow + 16*t + l15)*40 + quad*8];
      b[t] = *(const bf16x8*)&Bs[(64*wcol + 16*t + l15)*40 + quad*8];
    }
    #pragma unroll
    for (int ti=0;ti<4;ti++)
      #pragma unroll
      for (int tj=0;tj<4;tj++)
        acc[ti][tj] = __builtin_amdgcn_mfma_f32_16x16x32_bf16(a[ti], b[tj], acc[ti][tj], 0,0,0);
    __syncthreads();
  }

  const int colbase = n0 + 64*wcol;     // 64-aligned
  const int hh = colbase>>6;
  const int rowbase = m0 + 64*wrow + 4*quad;
  const float QSCALE = 0.18033688011112042f;  // log2(e)/8 folded into Q

  if (which < 2){
    u16* __restrict__ out = (which==0) ? Qr : Kr;
    const float osc = (which==0) ? QSCALE : 1.0f;
    #pragma unroll
    for (int tj=0;tj<4;tj++){
      int dd = 16*tj + l15;
      int obase = (dd>>5)*512 + ((dd>>3)&3)*128 + (dd&7);  // kh*512 + qd*128 + j
      float sgn = (tj<2) ? -1.0f : 1.0f;
      int pj = tj^2;
      #pragma unroll
      for (int ti=0;ti<4;ti++){
        #pragma unroll
        for (int r=0;r<4;r++){
          int m = rowbase + 16*ti + r;
          int bi = m>>11, si = m&2047;
          float cs = cosT[(si<<6)+dd];
          float sn = sinT[(si<<6)+dd];
          float vv = (acc[ti][tj][r]*cs + sgn*acc[ti][pj][r]*sn) * osc;
          out[((size_t)(bi*16+hh)<<17) + (si>>4)*1024 + (si&15)*8 + obase] = f2bf(vv);
        }
      }
    }
  } else {
    #pragma unroll
    for (int tj=0;tj<4;tj++){
      #pragma unroll
      for (int ti=0;ti<4;ti++){
        int m = rowbase + 16*ti;        // key base; r=0..3 consecutive keys
        int bi = m>>11, si = m&2047;
        ushort4 pk;
        pk.x = f2bf(acc[ti][tj][0]); pk.y = f2bf(acc[ti][tj][1]);
        pk.z = f2bf(acc[ti][tj][2]); pk.w = f2bf(acc[ti][tj][3]);
        *(ushort4*)&Vt[((size_t)(bi*16+hh)<<17) + (si>>6)*4096 + ((si>>5)&1)*2048
                       + tj*512 + ((si>>3)&3)*128 + l15*8 + (si&7)] = pk;
      }
    }
  }
}

// ---------------- flash attention v3: wave-autonomous, fragment-direct loads ----------------
// grid (16, 32 bh); block 256 = 4 waves = 2 q-tile-pair units; waves split k-tiles by parity.
// Tiles: 64 x 32-row q-tiles per bh; unit handles pair (p, 63-p) as 2 phases; merge via LDS once.
__global__ __launch_bounds__(256,2) void attn_k(const u16* __restrict__ QF, const u16* __restrict__ KF,
                                                const u16* __restrict__ VF, u16* __restrict__ ctx){
  __shared__ __align__(16) u16 Ps[4*2304];      // per-wave P scratch (32 x 72)
  __shared__ __align__(16) float OM[4][2304];   // merge buffers (64 x 36 f32), [uu*2 + ph]
  __shared__ float LL[4][32];                   // merge l partials
  const int tid = threadIdx.x;
  const int w = tid>>6, lane = tid&63, quad = lane>>4, l15 = lane&15;
  const int uu = w>>1, kpar = w&1;
  const int p = 2*blockIdx.x + uu;
  const int bh = blockIdx.y;
  const u16* __restrict__ Qb = QF + ((size_t)bh<<17);
  const u16* __restrict__ Kb = KF + ((size_t)bh<<17);
  const u16* __restrict__ Vb = VF + ((size_t)bh<<17);
  u16* __restrict__ Pw = Ps + w*2304;
  const int loff = lane*8;

  f32x4 o[2][2][4] = {};       // [phase][ti][tjd]
  float ls[2][2] = {{0.f,0.f},{0.f,0.f}};

  #pragma unroll 1
  for (int ph=0; ph<2; ph++){
    const int tile = ph ? (63-p) : p;
    const int q0 = tile*32;
    const int nk = (tile>>1) + 1;

    bf16x8 qf[2][2];
    #pragma unroll
    for (int ti=0;ti<2;ti++)
      #pragma unroll
      for (int kh=0;kh<2;kh++)
        qf[ti][kh] = *(const bf16x8*)&Qb[(2*tile+ti)*1024 + kh*512 + loff];

    for (int kt = kpar; kt < nk; kt += 2){
      const int k0 = kt*64;
      bf16x8 kf[4][2], vf[4][2];
      #pragma unroll
      for (int tjk=0;tjk<4;tjk++)
        #pragma unroll
        for (int kh=0;kh<2;kh++)
          kf[tjk][kh] = *(const bf16x8*)&Kb[(4*kt+tjk)*1024 + kh*512 + loff];
      #pragma unroll
      for (int tjd=0;tjd<4;tjd++)
        #pragma unroll
        for (int kh=0;kh<2;kh++)
          vf[tjd][kh] = *(const bf16x8*)&Vb[kt*4096 + kh*2048 + tjd*512 + loff];

      // S^T = K Q^T : col = q = l15, row = key = 16*tjk + 4*quad + r
      f32x4 st[2][4] = {};
      #pragma unroll
      for (int ti=0;ti<2;ti++)
        #pragma unroll
        for (int tjk=0;tjk<4;tjk++){
          st[ti][tjk] = __builtin_amdgcn_mfma_f32_16x16x32_bf16(kf[tjk][0], qf[ti][0], st[ti][tjk], 0,0,0);
          st[ti][tjk] = __builtin_amdgcn_mfma_f32_16x16x32_bf16(kf[tjk][1], qf[ti][1], st[ti][tjk], 0,0,0);
        }

      // max-free softmax (scale folded into Q): p = exp2(s), causal-masked on diagonal tiles
      #pragma unroll
      for (int ti=0;ti<2;ti++){
        const int qbase = q0 + 16*ti;
        f32x4 pv[4];
        if (k0 + 63 > qbase){                 // mask iff max key > min q-row of this 16-group
          const int qg = qbase + l15;
          #pragma unroll
          for (int tjk=0;tjk<4;tjk++)
            #pragma unroll
            for (int r=0;r<4;r++){
              int kg = k0 + 16*tjk + 4*quad + r;
              pv[tjk][r] = (kg > qg) ? 0.0f : exp2f(fminf(st[ti][tjk][r], 80.0f));
            }
        } else {
          #pragma unroll
          for (int tjk=0;tjk<4;tjk++)
            #pragma unroll
            for (int r=0;r<4;r++)
              pv[tjk][r] = exp2f(fminf(st[ti][tjk][r], 80.0f));
        }
        f32x4 t4 = (pv[0]+pv[1]) + (pv[2]+pv[3]);
        float rs = (t4[0]+t4[1]) + (t4[2]+t4[3]);
        rs += __shfl_xor(rs, 16, 64);
        rs += __shfl_xor(rs, 32, 64);
        ls[ph][ti] += rs;
        #pragma unroll
        for (int tjk=0;tjk<4;tjk++){
          ushort4 pk;
          pk.x = f2bf(pv[tjk][0]); pk.y = f2bf(pv[tjk][1]);
          pk.z = f2bf(pv[tjk][2]); pk.w = f2bf(pv[tjk][3]);
          *(ushort4*)&Pw[(16*ti + l15)*72 + 16*tjk + 4*quad] = pk;
        }
      }

      // O += P V
      bf16x8 pf[2][2];
      #pragma unroll
      for (int ti=0;ti<2;ti++)
        #pragma unroll
        for (int kh=0;kh<2;kh++)
          pf[ti][kh] = *(const bf16x8*)&Pw[(16*ti + l15)*72 + 32*kh + quad*8];
      #pragma unroll
      for (int ti=0;ti<2;ti++)
        #pragma unroll
        for (int tjd=0;tjd<4;tjd++){
          o[ph][ti][tjd] = __builtin_amdgcn_mfma_f32_16x16x32_bf16(pf[ti][0], vf[tjd][0], o[ph][ti][tjd], 0,0,0);
          o[ph][ti][tjd] = __builtin_amdgcn_mfma_f32_16x16x32_bf16(pf[ti][1], vf[tjd][1], o[ph][ti][tjd], 0,0,0);
        }
    }
  }

  // ---- merge partner waves (single barrier) ----
  // writer: my phase==kpar partial goes to LDS; merger: I finish phase 1-kpar and write ctx.
  const int wr_ph = kpar, mg_ph = 1 - kpar;
  float* __restrict__ Ob = OM[uu*2 + wr_ph];
  #pragma unroll
  for (int ti=0;ti<2;ti++)
    #pragma unroll
    for (int tjd=0;tjd<4;tjd++)
      *(f32x4*)&Ob[(16*tjd + l15)*36 + 16*ti + 4*quad] = o[wr_ph][ti][tjd];
  if (quad == 0){
    LL[uu*2 + wr_ph][l15]      = ls[wr_ph][0];
    LL[uu*2 + wr_ph][16 + l15] = ls[wr_ph][1];
  }
  __syncthreads();

  const float* __restrict__ Op = OM[uu*2 + mg_ph];
  const float* __restrict__ Lp = LL[uu*2 + mg_ph];
  const int tileO = mg_ph ? (63-p) : p;
  const int q0o = tileO*32;
  const int bi = bh>>4, hh = bh&15;
  #pragma unroll
  for (int ti=0;ti<2;ti++){
    f32x4 om[4];
    #pragma unroll
    for (int tjd=0;tjd<4;tjd++)
      om[tjd] = o[mg_ph][ti][tjd] + *(const f32x4*)&Op[(16*tjd + l15)*36 + 16*ti + 4*quad];
    #pragma unroll
    for (int r=0;r<4;r++){
      float lv = Lp[16*ti + 4*quad + r] + __shfl(ls[mg_ph][ti], 4*quad + r, 64);
      float inv = 1.0f / lv;
      int sq = q0o + 16*ti + 4*quad + r;
      u16* orow = ctx + (((size_t)(bi*2048 + sq))<<10) + (hh<<6);
      #pragma unroll
      for (int tjd=0;tjd<4;tjd++)
        orow[16*tjd + l15] = f2bf(om[tjd][r] * inv);
    }
  }
}

// ---------------- output GEMM: ctx @ W_o -> fp32 out ----------------
__global__ __launch_bounds__(256) void gemm_out_k(const u16* __restrict__ cb, const u16* __restrict__ Wot,
                                                  float* __restrict__ out){
  __shared__ __align__(16) u16 As[128*40];
  __shared__ __align__(16) u16 Bs[128*40];
  const int tid = threadIdx.x;
  const int w = tid>>6, lane = tid&63, quad = lane>>4, l15 = lane&15;
  const int wrow = w>>1, wcol = w&1;
  const int m0 = blockIdx.x*128;
  const int nG0 = blockIdx.y*128;
  f32x4 acc[4][4] = {};
  const int r0 = tid>>2, sg = (tid&3)*8;
  const int r1 = r0 + 64;

  for (int kb=0; kb<1024; kb+=32){
    *(uint4*)&As[r0*40 + sg] = *(const uint4*)&cb [(size_t)(m0+r0)*1024 + kb + sg];
    *(uint4*)&Bs[r0*40 + sg] = *(const uint4*)&Wot[(size_t)(nG0+r0)*1024 + kb + sg];
    *(uint4*)&As[r1*40 + sg] = *(const uint4*)&cb [(size_t)(m0+r1)*1024 + kb + sg];
    *(uint4*)&Bs[r1*40 + sg] = *(const uint4*)&Wot[(size_t)(nG0+r1)*1024 + kb + sg];
    __syncthreads();
    bf16x8 a[4], b[4];
    #pragma unroll
    for (int t=0;t<4;t++){
      a[t] = *(const bf16x8*)&As[(64*wrow + 16*t + l15)*40 + quad*8];
      b[t] = *(const bf16x8*)&Bs[(64*wcol + 16*t + l15)*40 + quad*8];
    }
    #pragma unroll
    for (int ti=0;ti<4;ti++)
      #pragma unroll
      for (int tj=0;tj<4;tj++)
        acc[ti][tj] = __builtin_amdgcn_mfma_f32_16x16x32_bf16(a[ti], b[tj], acc[ti][tj], 0,0,0);
    __syncthreads();
  }

  const int rowbase = m0 + 64*wrow + 4*quad;
  const int colb = nG0 + 64*wcol;
  #pragma unroll
  for (int ti=0;ti<4;ti++){
    #pragma unroll
    for (int r=0;r<4;r++){
      int m = rowbase + 16*ti + r;
      float* orow = out + (size_t)m*1024 + colb;
      #pragma unroll
      for (int tj=0;tj<4;tj++)
        orow[16*tj + l15] = acc[ti][tj][r];
    }
  }
}

extern "C" void kernel_launch(void* const* d_in, const int* in_sizes, int n_in,
                              void* d_out, int out_size, void* d_ws, size_t ws_size,
                              hipStream_t stream){
  const float* x  = (const float*)d_in[0];
  const float* Wq = (const float*)d_in[1];
  const float* Wk = (const float*)d_in[2];
  const float* Wv = (const float*)d_in[3];
  const float* Wo = (const float*)d_in[4];
  float* out = (float*)d_out;
  u16* ws = (u16*)d_ws;

  u16* XB  = ws;                    // x bf16            [4096][1024]   8 MB
  u16* WT  = ws + ((size_t)4<<20);  // Wq^T,Wk^T,Wv^T,Wo^T bf16         8 MB
  u16* QFp = ws + ((size_t)8<<20);  // Q fragments (roped+scaled)       8 MB
  u16* KFp = ws + ((size_t)12<<20); // K fragments (roped)              8 MB
  u16* VFp = ws + ((size_t)16<<20); // V fragments                      8 MB
  u16* CTX = ws + ((size_t)20<<20); // ctx bf16 [4096][1024]            8 MB
  float* COS = (float*)(ws + ((size_t)24<<20));  // [2048][64]          512 KB
  float* SIN = COS + (1<<17);                    //                     512 KB

  convert_x_k  <<<512, 256, 0, stream>>>(x, XB, 1<<20);
  transpose_w_k<<<dim3(32,32,4), dim3(32,8), 0, stream>>>(Wq, Wk, Wv, Wo, WT);
  rope_tables_k<<<512, 256, 0, stream>>>(COS, SIN);
  gemm_qkv_k   <<<dim3(32,24), 256, 0, stream>>>(XB, WT, COS, SIN, QFp, KFp, VFp);
  attn_k       <<<dim3(16,32), 256, 0, stream>>>(QFp, KFp, VFp, CTX);
  gemm_out_k   <<<dim3(32,8), 256, 0, stream>>>(CTX, WT + ((size_t)3<<20), out);
}